// Round 9
// baseline (246.562 us; speedup 1.0000x reference)
//
#include <hip/hip_runtime.h>
#include <math.h>

// MS-SSIM loss, 5 levels, 11-tap separable Gaussian (sigma=1.5), VALID padding.
// Round 9: barrier-free wave-private row streaming. Each wave owns a 64-col
// band (+10 halo) with a private single-slot LDS row buffer. LDS ops from one
// wave are processed in order by the DS pipe, so read-then-overwrite needs no
// sync; global prefetch rides vmcnt one iteration ahead. No __syncthreads in
// the hot loop; final reduce = wave shuffle + atomics.
// 4-map transform (a=x+y, b=x-y -> P,Q,U,V), x2-rescaled emit (exact).

#define RWW 76          // per-wave row width in float2{a,b} entries (74 used)

struct GWin { float w[11]; };

__global__ __launch_bounds__(256)
void ssim_rows_kernel(const float* __restrict__ X, const float* __restrict__ Y,
                      float* __restrict__ poolX, float* __restrict__ poolY,
                      float* __restrict__ accum,   // [0..95]=ssim, [96..191]=cs
                      int S, int outS, int doPool, int rps, GWin gw)
{
    __shared__ float2 ab[4][2][RWW];     // [wave][row01][floatcol] = {a, b}

    const int ch  = blockIdx.z;
    const int oy0 = blockIdx.x * rps;
    const int cb0 = blockIdx.y * 256;
    const int tid = threadIdx.x;
    const int w   = tid >> 6;            // wave id
    const int ln  = tid & 63;            // lane
    const int gb  = cb0 + w * 64;        // wave's base output float-col
    const int halfS = S >> 1;
    const int NIT = (rps + 10) >> 1;     // iterations, 2 input rows each

    const float* Xc = X + (size_t)ch * S * S;
    const float* Yc = Y + (size_t)ch * S * S;

    // staging decode: 74 float2-load tasks over 2 rows (37 per row)
    const int  r0_ = (ln < 37) ? 0 : 1;
    const int  c0  = (ln < 37) ? ln : ln - 37;   // float2 index within row
    const bool hasT1 = (ln < 10);
    const int  c1  = 27 + ln;                    // extra task: row 1

    float2 sx0, sy0, sx1, sy1;           // prefetched global data

    auto issue = [&](int baseRow) {
        {
            int gr = baseRow + r0_; if (gr > S - 1) gr = S - 1;
            const float* xr = Xc + (size_t)gr * S;
            const float* yr = Yc + (size_t)gr * S;
            int gc = gb + 2 * c0;
            if (gc + 1 < S) {
                sx0 = *reinterpret_cast<const float2*>(xr + gc);
                sy0 = *reinterpret_cast<const float2*>(yr + gc);
            } else {
                int g0 = gc < S ? gc : S - 1;
                sx0.x = xr[g0]; sx0.y = xr[S - 1];
                sy0.x = yr[g0]; sy0.y = yr[S - 1];
            }
        }
        if (hasT1) {
            int gr = baseRow + 1; if (gr > S - 1) gr = S - 1;
            const float* xr = Xc + (size_t)gr * S;
            const float* yr = Yc + (size_t)gr * S;
            int gc = gb + 2 * c1;
            if (gc + 1 < S) {
                sx1 = *reinterpret_cast<const float2*>(xr + gc);
                sy1 = *reinterpret_cast<const float2*>(yr + gc);
            } else {
                int g0 = gc < S ? gc : S - 1;
                sx1.x = xr[g0]; sx1.y = xr[S - 1];
                sy1.x = yr[g0]; sy1.y = yr[S - 1];
            }
        }
    };
    auto write_slot = [&]() {            // regs -> wave-private LDS, {a,b} interleaved
        float4 v0;
        v0.x = sx0.x + sy0.x; v0.y = sx0.x - sy0.x;
        v0.z = sx0.y + sy0.y; v0.w = sx0.y - sy0.y;
        *reinterpret_cast<float4*>(&ab[w][r0_][2 * c0]) = v0;
        if (hasT1) {
            float4 v1;
            v1.x = sx1.x + sy1.x; v1.y = sx1.x - sy1.x;
            v1.z = sx1.y + sy1.y; v1.w = sx1.y - sy1.y;
            *reinterpret_cast<float4*>(&ab[w][1][2 * c1]) = v1;
        }
    };

    // pending v-conv partials: 12 slots x {P,Q} + {U,V}, float2-packed
    float2 pendPQ[12], pendUV[12];
    #pragma unroll
    for (int i = 0; i < 12; ++i) { pendPQ[i] = make_float2(0.f, 0.f); pendUV[i] = make_float2(0.f, 0.f); }

    float ssum = 0.f, csum = 0.f;
    const float C1x2 = 2e-4f, C2x2 = 1.8e-3f;
    const bool colOK = (gb + ln) < outS;

    // prologue: rows 0-1 into the slot; rows 2-3 in flight
    issue(oy0);
    write_slot();
    issue(oy0 + 2);

    for (int k = 0; k < NIT; ++k) {
        // ---- h-conv reads of the slot (rows 2k, 2k+1): one b64 per tap ----
        float2 hPQ0 = make_float2(0.f, 0.f), hUV0 = make_float2(0.f, 0.f);
        float2 hPQ1 = make_float2(0.f, 0.f), hUV1 = make_float2(0.f, 0.f);
        #pragma unroll
        for (int t = 0; t < 11; ++t) {
            float wt = gw.w[t];
            float2 v = ab[w][0][ln + t];
            hPQ0.x = fmaf(wt, v.x, hPQ0.x);
            hPQ0.y = fmaf(wt, v.y, hPQ0.y);
            hUV0.x = fmaf(wt * v.x, v.x, hUV0.x);
            hUV0.y = fmaf(wt * v.y, v.y, hUV0.y);
        }
        #pragma unroll
        for (int t = 0; t < 11; ++t) {
            float wt = gw.w[t];
            float2 v = ab[w][1][ln + t];
            hPQ1.x = fmaf(wt, v.x, hPQ1.x);
            hPQ1.y = fmaf(wt, v.y, hPQ1.y);
            hUV1.x = fmaf(wt * v.x, v.x, hUV1.x);
            hUV1.y = fmaf(wt * v.y, v.y, hUV1.y);
        }

        // ---- 2x2 pool from the slot (before overwrite; wave-private) ----
        if (doPool && ln < 32 && k < (rps >> 1)) {
            float4 q0 = *reinterpret_cast<const float4*>(&ab[w][0][2 * ln]);
            float4 q1 = *reinterpret_cast<const float4*>(&ab[w][1][2 * ln]);
            float sa = q0.x + q0.z + q1.x + q1.z;
            float sb = q0.y + q0.w + q1.y + q1.w;
            int pc = (gb >> 1) + ln;
            if (pc < halfS) {
                int prow = (oy0 >> 1) + k;
                size_t o = (size_t)ch * halfS * halfS + (size_t)prow * halfS + pc;
                poolX[o] = 0.125f * (sa + sb);
                poolY[o] = 0.125f * (sa - sb);
            }
        }

        // ---- v-accumulate into pending ring ----
        #pragma unroll
        for (int j = 0; j <= 10; ++j) {          // row 2k: w[10-j] -> slot j
            float wt = gw.w[10 - j];
            pendPQ[j].x = fmaf(wt, hPQ0.x, pendPQ[j].x);
            pendPQ[j].y = fmaf(wt, hPQ0.y, pendPQ[j].y);
            pendUV[j].x = fmaf(wt, hUV0.x, pendUV[j].x);
            pendUV[j].y = fmaf(wt, hUV0.y, pendUV[j].y);
        }
        #pragma unroll
        for (int j = 1; j <= 11; ++j) {          // row 2k+1: w[11-j] -> slot j
            float wt = gw.w[11 - j];
            pendPQ[j].x = fmaf(wt, hPQ1.x, pendPQ[j].x);
            pendPQ[j].y = fmaf(wt, hPQ1.y, pendPQ[j].y);
            pendUV[j].x = fmaf(wt, hUV1.x, pendUV[j].x);
            pendUV[j].y = fmaf(wt, hUV1.y, pendUV[j].y);
        }

        // ---- emit 2 finished output rows (x2-rescaled algebra, exact) ----
        if (k >= 5) {
            #pragma unroll
            for (int e = 0; e < 2; ++e) {
                int orow = oy0 + 2 * k - 10 + e;
                float p = pendPQ[e].x, q = pendPQ[e].y;
                float u = pendUV[e].x, v = pendUV[e].y;
                float p2 = p * p, q2 = q * q;
                float A = p2 - q2;                         // 2*(2 mu12)
                float csn = (u - v - A) + C2x2;            // 2*(2 sigma12) + 2C2
                float csd = (u + v - p2 - q2) + C2x2;
                float cs  = csn * __builtin_amdgcn_rcpf(csd);
                float ss  = (A + C1x2) * __builtin_amdgcn_rcpf(p2 + q2 + C1x2) * cs;
                if (orow < outS && colOK) { ssum += ss; csum += cs; }
            }
        }

        // ---- shift ring by 2 slots ----
        #pragma unroll
        for (int j = 0; j < 10; ++j) { pendPQ[j] = pendPQ[j + 2]; pendUV[j] = pendUV[j + 2]; }
        pendPQ[10] = make_float2(0.f, 0.f); pendUV[10] = make_float2(0.f, 0.f);
        pendPQ[11] = make_float2(0.f, 0.f); pendUV[11] = make_float2(0.f, 0.f);

        // ---- overwrite slot with rows 2k+2..2k+3 (in-order DS: safe) ----
        if (k + 1 < NIT) {
            write_slot();                        // waits vmcnt for issue(k+1) data
            if (k + 2 < NIT) issue(oy0 + 2 * (k + 2));
        }
    }

    // ---- wave reduction + atomic accumulate (no barrier needed) ----
    for (int off = 32; off > 0; off >>= 1) {
        ssum += __shfl_down(ssum, off);
        csum += __shfl_down(csum, off);
    }
    if (ln == 0) {
        atomicAdd(&accum[ch], ssum);
        atomicAdd(&accum[96 + ch], csum);
    }
}

__global__ void finalize_kernel(const float* __restrict__ accum, float* __restrict__ out)
{
    __shared__ float red[2];
    const int t = threadIdx.x;   // 128 threads
    const float w[5]   = {0.0448f, 0.2856f, 0.3001f, 0.2363f, 0.1333f};
    const float inv[5] = {1.f / (502.f * 502.f), 1.f / (246.f * 246.f),
                          1.f / (118.f * 118.f), 1.f / (54.f * 54.f),
                          1.f / (22.f * 22.f)};
    float ms = 0.f;
    if (t < 96) {
        ms = 1.f;
        #pragma unroll
        for (int l = 0; l < 5; ++l) {
            float v = (l < 4) ? accum[l * 192 + 96 + t] : accum[l * 192 + t];
            v *= inv[l];
            v = fmaxf(v, 0.f);
            ms *= powf(v, w[l]);
        }
    }
    for (int off = 32; off > 0; off >>= 1) ms += __shfl_down(ms, off);
    int wid = t >> 6, lane = t & 63;
    if (lane == 0) red[wid] = ms;
    __syncthreads();
    if (t == 0) out[0] = 1.f - (red[0] + red[1]) * (1.f / 96.f);
}

extern "C" void kernel_launch(void* const* d_in, const int* in_sizes, int n_in,
                              void* d_out, int out_size, void* d_ws, size_t ws_size,
                              hipStream_t stream)
{
    (void)in_sizes; (void)n_in; (void)out_size; (void)ws_size;
    const float* X = (const float*)d_in[0];
    const float* Y = (const float*)d_in[1];
    float* out = (float*)d_out;
    float* ws  = (float*)d_ws;

    // Gaussian window (size 11, sigma 1.5), normalized
    GWin gw;
    {
        double g[11], s = 0.0;
        for (int i = 0; i < 11; ++i) { double d = i - 5; g[i] = exp(-(d * d) / 4.5); s += g[i]; }
        for (int i = 0; i < 11; ++i) gw.w[i] = (float)(g[i] / s);
    }

    // workspace layout (floats)
    float* accum = ws;                 // 5 levels * 192
    size_t off = 1024;
    float* p1x = ws + off; off += (size_t)96 * 256 * 256;
    float* p1y = ws + off; off += (size_t)96 * 256 * 256;
    float* p2x = ws + off; off += (size_t)96 * 128 * 128;
    float* p2y = ws + off; off += (size_t)96 * 128 * 128;
    float* p3x = ws + off; off += (size_t)96 * 64 * 64;
    float* p3y = ws + off; off += (size_t)96 * 64 * 64;
    float* p4x = ws + off; off += (size_t)96 * 32 * 32;
    float* p4y = ws + off; off += (size_t)96 * 32 * 32;

    hipMemsetAsync(accum, 0, 5 * 192 * sizeof(float), stream);

    auto launch = [&](const float* x, const float* y, float* px_, float* py_,
                      float* acc, int S, int outS, int pool) {
        int rps = (S >= 512) ? 64 : 32;               // output rows per block
        dim3 g((S + rps - 1) / rps, (S + 255) / 256, 96);
        ssim_rows_kernel<<<g, 256, 0, stream>>>(x, y, px_, py_, acc, S, outS, pool, rps, gw);
    };

    launch(X,   Y,   p1x, p1y, accum + 0,   512, 502, 1);
    launch(p1x, p1y, p2x, p2y, accum + 192, 256, 246, 1);
    launch(p2x, p2y, p3x, p3y, accum + 384, 128, 118, 1);
    launch(p3x, p3y, p4x, p4y, accum + 576, 64,  54,  1);
    launch(p4x, p4y, nullptr, nullptr, accum + 768, 32, 22, 0);

    finalize_kernel<<<1, 128, 0, stream>>>(accum, out);
}